// Round 6
// baseline (94.442 us; speedup 1.0000x reference)
//
#include <hip/hip_runtime.h>
#include <hip/hip_bf16.h>
#include <stdint.h>

// Problem constants
#define B_ 16
#define C_ 256
#define H_ 64
#define W_ 64
#define WP 66                  // padded width: w' = w+1, border cols 0 and 65 zero
#define HP 66                  // padded height: h' = h+1, border rows 0 and 65 zero
#define ROWB (WP * C_)         // bytes per padded row of fp8 signs = 16896
#define STAGEB (4 * ROWB)      // 4 rows staged contiguously = 67584

typedef __attribute__((ext_vector_type(4))) float f32x4;
typedef __attribute__((ext_vector_type(2))) long long2_t;

typedef const __attribute__((address_space(1))) uint32_t* gptr_t;
typedef __attribute__((address_space(3))) uint32_t* lptr_t;

__device__ __forceinline__ void gl_lds16(const void* g, void* l) {
  __builtin_amdgcn_global_load_lds((gptr_t)g, (lptr_t)l, 16, 0, 0);
}

// fp8 e4m3fn signs: +1 = 0x38, -1 = 0xB8, 0 = 0x00 (exact)
__device__ __forceinline__ uint8_t sgn8(float v) {
  return v > 0.f ? (uint8_t)0x38 : (v < 0.f ? (uint8_t)0xB8 : (uint8_t)0);
}

// ---------- kernel A: weight scale + fp8 signs, kc-paired b128 layout ----------
// wtb[t][ot][kcp][mi][lane][16] ; 16B = frag(kc=2kcp) || frag(kc=2kcp+1)
// o = ot*64 + mi*16 + lm ; frag(kc): c = kc*32 + lk*8 + j ; lane l = lk*16 + lm
__global__ void prep_w(const float* __restrict__ w, float* __restrict__ scale,
                       uint8_t* __restrict__ wtb) {
  int o = blockIdx.x, c = threadIdx.x;
  const float* wo = w + (size_t)o * 2304 + (size_t)c * 9;  // w[o][c][kh][kw]
  float v[9];
  float s = 0.f;
#pragma unroll
  for (int t = 0; t < 9; ++t) { v[t] = wo[t]; s += fabsf(v[t]); }
  __shared__ float red[256];
  red[c] = s;
  __syncthreads();
  for (int st = 128; st > 0; st >>= 1) {
    if (c < st) red[c] += red[c + st];
    __syncthreads();
  }
  if (c == 0) scale[o] = red[0] / 2304.0f;
  int ot = o >> 6, mi = (o >> 4) & 3, lm = o & 15;
  int kcp = c >> 6, half = (c >> 5) & 1, lk = (c >> 3) & 3, j = c & 7;
  int l = lk * 16 + lm;
#pragma unroll
  for (int t = 0; t < 9; ++t)
    wtb[((((size_t)t * 4 + ot) * 4 + kcp) * 4 + mi) * 1024 + l * 16 + half * 8 + j] =
        sgn8(v[t]);
}

// ---------- kernel B: binarize + transpose to swizzled padded fp8 layout ----------
// a_p row index = b*66 + (h+1); per row 66 pixel-blocks of 256B = 16 chunks of 16B.
// chunk c16 = kcp*4 + lk holds c[kcp*64+lk*8 ..+8] || c[kcp*64+32+lk*8 ..+8].
// stored chunk = c16 ^ (w' & 15).
__global__ void binarize(const float* __restrict__ x, const float* __restrict__ bias,
                         uint8_t* __restrict__ a_p) {
  int bh = blockIdx.x, b = bh >> 6, h = bh & 63, c0 = blockIdx.y * 64;
  int tid = threadIdx.x;
  __shared__ uint8_t lt[64][72];  // [w][ci]
#pragma unroll
  for (int p = 0; p < 4; ++p) {
    int ci = p * 16 + (tid >> 4), w4 = (tid & 15) * 4;
    f32x4 v = *(const f32x4*)(x + (((size_t)(b * C_ + c0 + ci) * H_ + h) * W_ + w4));
    float bb = bias[c0 + ci];
#pragma unroll
    for (int k = 0; k < 4; ++k) lt[w4 + k][ci] = sgn8(v[k] + bb);
  }
  __syncthreads();
  size_t rowbase = (size_t)(b * HP + h + 1) * ROWB;
#pragma unroll
  for (int p = 0; p < 4; ++p) {
    int w = p * 16 + (tid >> 4), cp = (tid & 15) * 4, c = c0 + cp;
    uint32_t val = (uint32_t)lt[w][cp] | ((uint32_t)lt[w][cp + 1] << 8) |
                   ((uint32_t)lt[w][cp + 2] << 16) | ((uint32_t)lt[w][cp + 3] << 24);
    int wp = w + 1;
    int c16 = ((c >> 6) << 2) | ((c >> 3) & 3);
    int half = (c >> 5) & 1;
    int pos = wp * 256 + ((c16 ^ wp) & 15) * 16 + half * 8 + (c & 7);
    *(uint32_t*)(a_p + rowbase + pos) = val;
  }
  // zero border columns of this row; for edge h, zero the padded border rows.
  if (blockIdx.y == 0) {
    if (tid < 64) *(uint32_t*)(a_p + rowbase + tid * 4) = 0;
    else if (tid < 128) *(uint32_t*)(a_p + rowbase + 65 * 256 + (tid - 64) * 4) = 0;
  }
  if (h == 0) {  // zero row h'=0 (quarter per y-block)
    uint32_t* zr = (uint32_t*)(a_p + (size_t)b * HP * ROWB) + blockIdx.y * 1056;
    for (int k = tid; k < 1056; k += 256) zr[k] = 0;
  } else if (h == 63) {  // zero row h'=65
    uint32_t* zr = (uint32_t*)(a_p + ((size_t)b * HP + 65) * ROWB) + blockIdx.y * 1056;
    for (int k = tid; k < 1056; k += 256) zr[k] = 0;
  }
}

// ---------- kernel C: binary conv via fp8 MFMA, M=128 x N=128 blocks ----------
// Block = (p, b, hp): output channels [p*128, p*128+128), rows h=2*hp, h+1.
// 4 waves: oq = wv&1 (channel 64-group within half), ro = wv>>1 (row offset).
// LDS: 4 padded rows h'..h'+3 (h' = h). 2 blocks/CU resident, 1024 blocks
// = exactly 2 rounds -> no packing tail (round-5 MfmaUtil=46% diagnosis).
#define LOADW(dst, t, kcp) {                                                      \
  const uint8_t* wb_ = wtb + ((((size_t)(t) * 4 + ot) * 4 + (kcp)) * 4) * 1024 + l * 16; \
  _Pragma("unroll") for (int mi = 0; mi < 4; ++mi)                                \
      dst[mi] = *(const long2_t*)(wb_ + mi * 1024); }

#define LOADB(dst, d, dxi, kcp) {                                                 \
  int sw_ = (((kcp) * 4 + lk) ^ (lm + (dxi))) & 15;                               \
  const uint8_t* bb_ = smem + (d) * ROWB + (lm + (dxi)) * 256 + sw_ * 16;         \
  _Pragma("unroll") for (int ni = 0; ni < 4; ++ni)                                \
      dst[ni] = *(const long2_t*)(bb_ + ni * 4096); }

__global__ __launch_bounds__(256, 2) void bconv(
    const uint8_t* __restrict__ a_p, const uint8_t* __restrict__ wtb,
    const float* __restrict__ scale, const float* __restrict__ x,
    const float* __restrict__ pb0, const float* __restrict__ alpha,
    const float* __restrict__ pb1, float* __restrict__ out) {
  __shared__ __attribute__((aligned(16))) uint8_t smem[STAGEB];
  // XCD-aware bijective swizzle: 1024 blocks, 8 XCDs, 128 contiguous per XCD
  int bh = (blockIdx.x & 7) * 128 + (blockIdx.x >> 3);
  // p toggles fastest so the (p=0,p=1) pair sharing staged rows is co-scheduled
  int p = bh & 1, b = bh >> 6, hp = (bh >> 1) & 31, h = hp * 2;
  int tid = threadIdx.x, l = tid & 63, wv = tid >> 6;
  int lm = l & 15, lk = l >> 4;
  int oq = wv & 1, ro = wv >> 1;
  int ot = p * 2 + oq;            // wtb quarter index (o>>6)
  int wm = ot * 64;               // output channel base for this wave

  // stage 4 contiguous padded rows (h'..h'+3) = input rows h-1..h+2
  const uint8_t* src = a_p + (size_t)(b * HP + h) * ROWB;
#pragma unroll
  for (int it = 0; it < 16; ++it)
    gl_lds16(src + (size_t)(it * 256 + tid) * 16, smem + it * 4096 + wv * 1024);
  if (tid < 128) gl_lds16(src + (size_t)(4096 + tid) * 16, smem + 65536 + wv * 1024);

  f32x4 acc[4][4];
#pragma unroll
  for (int i = 0; i < 4; ++i)
#pragma unroll
    for (int j = 0; j < 4; ++j) acc[i][j] = (f32x4){0.f, 0.f, 0.f, 0.f};

  asm volatile("s_waitcnt vmcnt(0)" ::: "memory");
  __syncthreads();

  long2_t wc[4], bc[4], wn[4], bn[4];
  LOADW(wc, 0, 0)
  LOADB(bc, ro, 0, 0)
#pragma unroll 1
  for (int t = 0; t < 9; ++t) {      // tap loop NOT unrolled: fences code motion
#pragma unroll
    for (int kcp = 0; kcp < 4; ++kcp) {
      if (kcp < 3) {                 // prefetch next kcp of same tap
        int d = t / 3 + ro, dxi = t % 3;
        LOADW(wn, t, kcp + 1)
        LOADB(bn, d, dxi, kcp + 1)
      } else if (t < 8) {            // prefetch first kcp of next tap
        int t1 = t + 1, d1 = t1 / 3 + ro, dxi1 = t1 % 3;
        LOADW(wn, t1, 0)
        LOADB(bn, d1, dxi1, 0)
      }
#pragma unroll
      for (int mi = 0; mi < 4; ++mi)
#pragma unroll
        for (int ni = 0; ni < 4; ++ni) {
          acc[mi][ni] = __builtin_amdgcn_mfma_f32_16x16x32_fp8_fp8(
              wc[mi][0], bc[ni][0], acc[mi][ni], 0, 0, 0);
          acc[mi][ni] = __builtin_amdgcn_mfma_f32_16x16x32_fp8_fp8(
              wc[mi][1], bc[ni][1], acc[mi][ni], 0, 0, 0);
        }
#pragma unroll
      for (int q = 0; q < 4; ++q) { wc[q] = wn[q]; bc[q] = bn[q]; }
    }
  }

  // epilogue: conv*scale + pb0 -> PReLU -> + pb1 + x (residual); row = h + ro
  size_t xb = (size_t)b * C_ * H_ * W_ + (size_t)(h + ro) * W_;
#pragma unroll
  for (int mi = 0; mi < 4; ++mi) {
#pragma unroll
    for (int j = 0; j < 4; ++j) {
      int o = wm + mi * 16 + lk * 4 + j;  // C/D row = (lane>>4)*4 + reg
      float sc = scale[o], b0 = pb0[o], al = alpha[o], b1 = pb1[o];
      size_t rowo = xb + (size_t)o * (H_ * W_);
#pragma unroll
      for (int ni = 0; ni < 4; ++ni) {
        int wcol = ni * 16 + lm;          // C/D col = lane&15
        float v = acc[mi][ni][j] * sc + b0;
        v = v >= 0.f ? v : al * v;
        v = v + b1 + x[rowo + wcol];
        out[rowo + wcol] = v;
      }
    }
  }
}

extern "C" void kernel_launch(void* const* d_in, const int* in_sizes, int n_in,
                              void* d_out, int out_size, void* d_ws, size_t ws_size,
                              hipStream_t stream) {
  const float* x     = (const float*)d_in[0];
  const float* m0b   = (const float*)d_in[1];
  const float* w     = (const float*)d_in[2];
  const float* pb0   = (const float*)d_in[3];
  const float* alpha = (const float*)d_in[4];
  const float* pb1   = (const float*)d_in[5];
  float* out = (float*)d_out;

  // ws: [0,4KB) scale | [4096, +589824) wtb fp8 | a_p padded 16*66*16896 = 17.8MB
  float* scale = (float*)d_ws;
  uint8_t* wtb = (uint8_t*)d_ws + 4096;
  uint8_t* a_p = (uint8_t*)d_ws + 4096 + (size_t)9 * 4 * 4 * 4 * 1024;

  hipLaunchKernelGGL(prep_w, dim3(C_), dim3(256), 0, stream, w, scale, wtb);
  hipLaunchKernelGGL(binarize, dim3(B_ * H_, C_ / 64), dim3(256), 0, stream, x, m0b, a_p);
  hipLaunchKernelGGL(bconv, dim3(B_ * H_), dim3(256), 0, stream,
                     a_p, wtb, scale, x, pb0, alpha, pb1, out);
}

// Round 7
// 71.766 us; speedup vs baseline: 1.3160x; 1.3160x over previous
//
#include <hip/hip_runtime.h>
#include <hip/hip_bf16.h>
#include <stdint.h>

// Problem constants
#define B_ 16
#define C_ 256
#define H_ 64
#define W_ 64
#define WP 66                  // padded width: w' = w+1, border cols 0 and 65 zero
#define HP 66                  // padded height: h' = h+1, border rows 0 and 65 zero
#define ROWB (WP * C_)         // bytes per padded row of fp8 signs = 16896
#define STAGEB (3 * ROWB)      // 3 rows staged contiguously = 50688

typedef __attribute__((ext_vector_type(4))) float f32x4;
typedef __attribute__((ext_vector_type(2))) long long2_t;

typedef const __attribute__((address_space(1))) uint32_t* gptr_t;
typedef __attribute__((address_space(3))) uint32_t* lptr_t;

__device__ __forceinline__ void gl_lds16(const void* g, void* l) {
  __builtin_amdgcn_global_load_lds((gptr_t)g, (lptr_t)l, 16, 0, 0);
}

// fp8 e4m3fn signs: +1 = 0x38, -1 = 0xB8, 0 = 0x00 (exact)
__device__ __forceinline__ uint8_t sgn8(float v) {
  return v > 0.f ? (uint8_t)0x38 : (v < 0.f ? (uint8_t)0xB8 : (uint8_t)0);
}

// ---------- kernel A: weight scale + fp8 signs, kc-paired b128 layout ----------
// wtb[t][ot][kcp][mi][lane][16] ; 16B = frag(kc=2kcp) || frag(kc=2kcp+1)
// o = ot*64 + mi*16 + lm ; frag(kc): c = kc*32 + lk*8 + j ; lane l = lk*16 + lm
__global__ void prep_w(const float* __restrict__ w, float* __restrict__ scale,
                       uint8_t* __restrict__ wtb) {
  int o = blockIdx.x, c = threadIdx.x;
  const float* wo = w + (size_t)o * 2304 + (size_t)c * 9;  // w[o][c][kh][kw]
  float v[9];
  float s = 0.f;
#pragma unroll
  for (int t = 0; t < 9; ++t) { v[t] = wo[t]; s += fabsf(v[t]); }
  __shared__ float red[256];
  red[c] = s;
  __syncthreads();
  for (int st = 128; st > 0; st >>= 1) {
    if (c < st) red[c] += red[c + st];
    __syncthreads();
  }
  if (c == 0) scale[o] = red[0] / 2304.0f;
  int ot = o >> 6, mi = (o >> 4) & 3, lm = o & 15;
  int kcp = c >> 6, half = (c >> 5) & 1, lk = (c >> 3) & 3, j = c & 7;
  int l = lk * 16 + lm;
#pragma unroll
  for (int t = 0; t < 9; ++t)
    wtb[((((size_t)t * 4 + ot) * 4 + kcp) * 4 + mi) * 1024 + l * 16 + half * 8 + j] =
        sgn8(v[t]);
}

// ---------- kernel B: binarize + transpose to swizzled padded fp8 layout ----------
// a_p row index = b*66 + (h+1); per row 66 pixel-blocks of 256B = 16 chunks of 16B.
// chunk c16 = kcp*4 + lk holds c[kcp*64+lk*8 ..+8] || c[kcp*64+32+lk*8 ..+8].
// stored chunk = c16 ^ (w' & 15).
__global__ void binarize(const float* __restrict__ x, const float* __restrict__ bias,
                         uint8_t* __restrict__ a_p) {
  int bh = blockIdx.x, b = bh >> 6, h = bh & 63, c0 = blockIdx.y * 64;
  int tid = threadIdx.x;
  __shared__ uint8_t lt[64][72];  // [w][ci]
#pragma unroll
  for (int p = 0; p < 4; ++p) {
    int ci = p * 16 + (tid >> 4), w4 = (tid & 15) * 4;
    f32x4 v = *(const f32x4*)(x + (((size_t)(b * C_ + c0 + ci) * H_ + h) * W_ + w4));
    float bb = bias[c0 + ci];
#pragma unroll
    for (int k = 0; k < 4; ++k) lt[w4 + k][ci] = sgn8(v[k] + bb);
  }
  __syncthreads();
  size_t rowbase = (size_t)(b * HP + h + 1) * ROWB;
#pragma unroll
  for (int p = 0; p < 4; ++p) {
    int w = p * 16 + (tid >> 4), cp = (tid & 15) * 4, c = c0 + cp;
    uint32_t val = (uint32_t)lt[w][cp] | ((uint32_t)lt[w][cp + 1] << 8) |
                   ((uint32_t)lt[w][cp + 2] << 16) | ((uint32_t)lt[w][cp + 3] << 24);
    int wp = w + 1;
    int c16 = ((c >> 6) << 2) | ((c >> 3) & 3);
    int half = (c >> 5) & 1;
    int pos = wp * 256 + ((c16 ^ wp) & 15) * 16 + half * 8 + (c & 7);
    *(uint32_t*)(a_p + rowbase + pos) = val;
  }
  // zero border columns of this row; for edge h, zero the padded border rows.
  if (blockIdx.y == 0) {
    if (tid < 64) *(uint32_t*)(a_p + rowbase + tid * 4) = 0;
    else if (tid < 128) *(uint32_t*)(a_p + rowbase + 65 * 256 + (tid - 64) * 4) = 0;
  }
  if (h == 0) {  // zero row h'=0 (quarter per y-block)
    uint32_t* zr = (uint32_t*)(a_p + (size_t)b * HP * ROWB) + blockIdx.y * 1056;
    for (int k = tid; k < 1056; k += 256) zr[k] = 0;
  } else if (h == 63) {  // zero row h'=65
    uint32_t* zr = (uint32_t*)(a_p + ((size_t)b * HP + 65) * ROWB) + blockIdx.y * 1056;
    for (int k = tid; k < 1056; k += 256) zr[k] = 0;
  }
}

// ---------- kernel C: binary conv via fp8 MFMA, b128 frags, pipelined ----------
// Round-5 structure (best known). Round-7 deltas: (a) MFMA halves split into
// two 16-MFMA passes so no consecutive MFMAs share an accumulator (dependent
// back-to-back pairs were throttling issue); (b) s_setprio around the burst.
#define LOADW(dst, t, kcp) {                                                      \
  const uint8_t* wb_ = wtb + ((((size_t)(t) * 4 + wv) * 4 + (kcp)) * 4) * 1024 + l * 16; \
  _Pragma("unroll") for (int mi = 0; mi < 4; ++mi)                                \
      dst[mi] = *(const long2_t*)(wb_ + mi * 1024); }

#define LOADB(dst, d, dxi, kcp) {                                                 \
  int sw_ = (((kcp) * 4 + lk) ^ (lm + (dxi))) & 15;                               \
  const uint8_t* bb_ = smem + (d) * ROWB + (lm + (dxi)) * 256 + sw_ * 16;         \
  _Pragma("unroll") for (int ni = 0; ni < 4; ++ni)                                \
      dst[ni] = *(const long2_t*)(bb_ + ni * 4096); }

__global__ __launch_bounds__(256, 3) void bconv(
    const uint8_t* __restrict__ a_p, const uint8_t* __restrict__ wtb,
    const float* __restrict__ scale, const float* __restrict__ x,
    const float* __restrict__ pb0, const float* __restrict__ alpha,
    const float* __restrict__ pb1, float* __restrict__ out) {
  __shared__ __attribute__((aligned(16))) uint8_t smem[STAGEB];
  // XCD-aware bijective swizzle: 1024 blocks, 8 XCDs, 128 contiguous per XCD
  int bh = (blockIdx.x & 7) * 128 + (blockIdx.x >> 3);
  int b = bh >> 6, h = bh & 63;
  int tid = threadIdx.x, l = tid & 63, wv = tid >> 6;
  int lm = l & 15, lk = l >> 4;
  int wm = wv * 64;

  // stage 3 contiguous padded rows (h', h'+1, h'+2) = input rows h-1,h,h+1
  const uint8_t* src = a_p + (size_t)(b * HP + h) * ROWB;
#pragma unroll
  for (int it = 0; it < 12; ++it)
    gl_lds16(src + (size_t)(it * 256 + tid) * 16, smem + it * 4096 + wv * 1024);
  if (tid < 96) gl_lds16(src + 49152 + (size_t)tid * 16, smem + 49152 + wv * 1024);

  f32x4 acc[4][4];
#pragma unroll
  for (int i = 0; i < 4; ++i)
#pragma unroll
    for (int j = 0; j < 4; ++j) acc[i][j] = (f32x4){0.f, 0.f, 0.f, 0.f};

  asm volatile("s_waitcnt vmcnt(0)" ::: "memory");
  __syncthreads();

  long2_t wc[4], bc[4], wn[4], bn[4];
  LOADW(wc, 0, 0)
  LOADB(bc, 0, 0, 0)
#pragma unroll 1
  for (int t = 0; t < 9; ++t) {      // tap loop NOT unrolled: fences code motion
#pragma unroll
    for (int kcp = 0; kcp < 4; ++kcp) {
      if (kcp < 3) {                 // prefetch next kcp of same tap
        int d = t / 3, dxi = t % 3;
        LOADW(wn, t, kcp + 1)
        LOADB(bn, d, dxi, kcp + 1)
      } else if (t < 8) {            // prefetch first kcp of next tap
        int t1 = t + 1, d1 = t1 / 3, dxi1 = t1 - d1 * 3;
        LOADW(wn, t1, 0)
        LOADB(bn, d1, dxi1, 0)
      }
      __builtin_amdgcn_s_setprio(1);
      // pass 1: all [0]-half MFMAs (16 independent accumulators)
#pragma unroll
      for (int mi = 0; mi < 4; ++mi)
#pragma unroll
        for (int ni = 0; ni < 4; ++ni)
          acc[mi][ni] = __builtin_amdgcn_mfma_f32_16x16x32_fp8_fp8(
              wc[mi][0], bc[ni][0], acc[mi][ni], 0, 0, 0);
      // pass 2: all [1]-half MFMAs (dependent partner is 15 MFMAs away)
#pragma unroll
      for (int mi = 0; mi < 4; ++mi)
#pragma unroll
        for (int ni = 0; ni < 4; ++ni)
          acc[mi][ni] = __builtin_amdgcn_mfma_f32_16x16x32_fp8_fp8(
              wc[mi][1], bc[ni][1], acc[mi][ni], 0, 0, 0);
      __builtin_amdgcn_s_setprio(0);
#pragma unroll
      for (int q = 0; q < 4; ++q) { wc[q] = wn[q]; bc[q] = bn[q]; }
    }
  }

  // epilogue: conv*scale + pb0 -> PReLU -> + pb1 + x (residual)
  size_t xb = (size_t)b * C_ * H_ * W_ + (size_t)h * W_;
#pragma unroll
  for (int mi = 0; mi < 4; ++mi) {
#pragma unroll
    for (int j = 0; j < 4; ++j) {
      int o = wm + mi * 16 + lk * 4 + j;  // C/D row = (lane>>4)*4 + reg
      float sc = scale[o], b0 = pb0[o], al = alpha[o], b1 = pb1[o];
      size_t rowo = xb + (size_t)o * (H_ * W_);
#pragma unroll
      for (int ni = 0; ni < 4; ++ni) {
        int wcol = ni * 16 + lm;          // C/D col = lane&15
        float v = acc[mi][ni][j] * sc + b0;
        v = v >= 0.f ? v : al * v;
        v = v + b1 + x[rowo + wcol];
        out[rowo + wcol] = v;
      }
    }
  }
}

extern "C" void kernel_launch(void* const* d_in, const int* in_sizes, int n_in,
                              void* d_out, int out_size, void* d_ws, size_t ws_size,
                              hipStream_t stream) {
  const float* x     = (const float*)d_in[0];
  const float* m0b   = (const float*)d_in[1];
  const float* w     = (const float*)d_in[2];
  const float* pb0   = (const float*)d_in[3];
  const float* alpha = (const float*)d_in[4];
  const float* pb1   = (const float*)d_in[5];
  float* out = (float*)d_out;

  // ws: [0,4KB) scale | [4096, +589824) wtb fp8 | a_p padded 16*66*16896 = 17.8MB
  float* scale = (float*)d_ws;
  uint8_t* wtb = (uint8_t*)d_ws + 4096;
  uint8_t* a_p = (uint8_t*)d_ws + 4096 + (size_t)9 * 4 * 4 * 4 * 1024;

  hipLaunchKernelGGL(prep_w, dim3(C_), dim3(256), 0, stream, w, scale, wtb);
  hipLaunchKernelGGL(binarize, dim3(B_ * H_, C_ / 64), dim3(256), 0, stream, x, m0b, a_p);
  hipLaunchKernelGGL(bconv, dim3(B_ * H_), dim3(256), 0, stream,
                     a_p, wtb, scale, x, pb0, alpha, pb1, out);
}